// Round 6
// baseline (1406.021 us; speedup 1.0000x reference)
//
#include <hip/hip_runtime.h>

#define T_DIM 2048
#define B_DIM 16
#define D_DIM 1024
#define M_DIM (T_DIM * B_DIM)   // 32768 rows of x
#define K2    2048              // split K: [hi | lo]
#define N3    3072              // W_x | W_delta | W_gate output columns

typedef unsigned short u16;
typedef __bf16 bf16x8 __attribute__((ext_vector_type(8)));
typedef float  f32x4  __attribute__((ext_vector_type(4)));

typedef __attribute__((address_space(3))) uint32_t       lds_u32_t;
typedef const __attribute__((address_space(1))) uint32_t glb_u32_t;

__device__ inline void gload16(const void* g, void* l) {
  __builtin_amdgcn_global_load_lds((glb_u32_t*)g, (lds_u32_t*)l, 16, 0, 0);
}

// bf16 round-to-nearest-even, bit-level (inputs finite)
__device__ inline u16 f2bf_u(float f) {
  uint32_t u = __float_as_uint(f);
  uint32_t r = (u + 0x7FFFu + ((u >> 16) & 1u)) >> 16;
  return (u16)r;
}
__device__ inline float bfu2f(u16 u) {
  return __uint_as_float(((uint32_t)u) << 16);
}

// ---------------- convert x -> Xs [M, 2048] bf16 (hi | lo) ----------------
__global__ void cvt_x_kernel(const float* __restrict__ x, u16* __restrict__ Xs) {
  int i = blockIdx.x * 256 + threadIdx.x;          // 8,388,608 float4s
  int m  = i >> 8;                                 // 256 float4 per row
  int c4 = (i & 255) << 2;
  float4 v = reinterpret_cast<const float4*>(x)[i];
  float f[4] = {v.x, v.y, v.z, v.w};
  u16 hi[4], lo[4];
#pragma unroll
  for (int j = 0; j < 4; ++j) {
    hi[j] = f2bf_u(f[j]);
    lo[j] = f2bf_u(f[j] - bfu2f(hi[j]));
  }
  u16* base = Xs + (size_t)m * K2 + c4;
  *reinterpret_cast<ushort4*>(base)        = make_ushort4(hi[0], hi[1], hi[2], hi[3]);
  *reinterpret_cast<ushort4*>(base + 1024) = make_ushort4(lo[0], lo[1], lo[2], lo[3]);
}

// ------------- convert W_x|W_delta|W_gate -> Ws [3072, 2048] --------------
__global__ void cvt_w_kernel(const float* __restrict__ Wx, const float* __restrict__ Wd,
                             const float* __restrict__ Wg, u16* __restrict__ Ws) {
  int i = blockIdx.x * 256 + threadIdx.x;          // 786,432 float4s
  int n  = i >> 8;                                 // 0..3071
  int c4 = (i & 255) << 2;
  const float* W = (n < 1024) ? Wx : (n < 2048 ? Wd : Wg);
  int row = n & 1023;
  float4 v = reinterpret_cast<const float4*>(W)[(size_t)row * 256 + (i & 255)];
  float f[4] = {v.x, v.y, v.z, v.w};
  u16 hi[4], lo[4];
#pragma unroll
  for (int j = 0; j < 4; ++j) {
    hi[j] = f2bf_u(f[j]);
    lo[j] = f2bf_u(f[j] - bfu2f(hi[j]));
  }
  u16* base = Ws + (size_t)n * K2 + c4;
  *reinterpret_cast<ushort4*>(base)        = make_ushort4(hi[0], hi[1], hi[2], hi[3]);
  *reinterpret_cast<ushort4*>(base + 1024) = make_ushort4(lo[0], lo[1], lo[2], lo[3]);
}

// ---------------- GEMM: C[32768, 3072] = Xs · Wsᵀ (split 3-pass) ----------
// 128x128 tile, BK=64, 4 waves (2x2), mfma_f32_16x16x32_bf16.
// LDS tiles [128][64] bf16, XOR-swizzled: chunk' = chunk ^ (row & 7); linear
// global_load_lds dest + pre-swizzled global source + swizzled ds_read.
__global__ __launch_bounds__(256) void gemm_kernel(const u16* __restrict__ Xs,
                                                   const u16* __restrict__ Ws,
                                                   float* __restrict__ C) {
  __shared__ __align__(16) u16 As[128 * 64];
  __shared__ __align__(16) u16 Bs[128 * 64];

  int bid = blockIdx.x;
  int swz = (bid & 7) * 768 + (bid >> 3);   // 6144 % 8 == 0 -> bijective
  int nt = swz >> 8;                        // 0..23
  int mt = swz & 255;                       // 0..255
  int tid  = threadIdx.x;
  int lane = tid & 63;
  int wid  = tid >> 6;
  int wr = wid >> 1, wc = wid & 1;
  int r16 = lane & 15, grp = lane >> 4;

  f32x4 acc[4][4];
#pragma unroll
  for (int m = 0; m < 4; ++m)
#pragma unroll
    for (int n = 0; n < 4; ++n)
#pragma unroll
      for (int e = 0; e < 4; ++e) acc[m][n][e] = 0.0f;

  const u16* Abase = Xs + (size_t)mt * 128 * K2;
  const u16* Bbase = Ws + (size_t)nt * 128 * K2;

#pragma unroll 1
  for (int p = 0; p < 3; ++p) {
    const u16* Ap = Abase + (p == 2 ? 1024 : 0);  // passes: hi·hi, hi·lo, lo·hi
    const u16* Bp = Bbase + (p == 1 ? 1024 : 0);
#pragma unroll 1
    for (int kt = 0; kt < 16; ++kt) {
      __syncthreads();  // all waves done reading previous tile
#pragma unroll
      for (int i = 0; i < 4; ++i) {
        int slot = i * 256 + tid;
        int row  = slot >> 3;
        int c    = (slot & 7) ^ (row & 7);
        gload16(Ap + (size_t)row * K2 + kt * 64 + c * 8,
                &As[(size_t)(i * 256 + wid * 64) * 8]);
      }
#pragma unroll
      for (int i = 0; i < 4; ++i) {
        int slot = i * 256 + tid;
        int row  = slot >> 3;
        int c    = (slot & 7) ^ (row & 7);
        gload16(Bp + (size_t)row * K2 + kt * 64 + c * 8,
                &Bs[(size_t)(i * 256 + wid * 64) * 8]);
      }
      __syncthreads();  // drains vmcnt(0): staged data visible
#pragma unroll
      for (int ks = 0; ks < 2; ++ks) {
        bf16x8 af[4], bfr[4];
#pragma unroll
        for (int m = 0; m < 4; ++m) {
          int row = wr * 64 + m * 16 + r16;
          int ch  = (ks * 4 + grp) ^ (row & 7);
          af[m] = *reinterpret_cast<const bf16x8*>(&As[row * 64 + ch * 8]);
        }
#pragma unroll
        for (int n = 0; n < 4; ++n) {
          int row = wc * 64 + n * 16 + r16;
          int ch  = (ks * 4 + grp) ^ (row & 7);
          bfr[n] = *reinterpret_cast<const bf16x8*>(&Bs[row * 64 + ch * 8]);
        }
#pragma unroll
        for (int m = 0; m < 4; ++m)
#pragma unroll
          for (int n = 0; n < 4; ++n)
            acc[m][n] = __builtin_amdgcn_mfma_f32_16x16x32_bf16(af[m], bfr[n], acc[m][n], 0, 0, 0);
      }
    }
  }

  // epilogue: C/D layout col = lane&15, row = (lane>>4)*4 + reg  [HW-verified]
  size_t baseRow = (size_t)mt * 128 + wr * 64 + grp * 4;
  int    baseCol = nt * 128 + wc * 64 + r16;
#pragma unroll
  for (int m = 0; m < 4; ++m)
#pragma unroll
    for (int reg = 0; reg < 4; ++reg) {
      float* crow = C + (baseRow + m * 16 + reg) * (size_t)N3 + baseCol;
#pragma unroll
      for (int n = 0; n < 4; ++n) crow[n * 16] = acc[m][n][reg];
    }
}

// ---------------- scan: 16384 independent chains over T=2048 --------------
// 1 wave/CU (no TLP): latency hidden purely by outstanding-load depth.
// Little's law: 6.3 TB/s x 375 ns ~ 2.4 MB in flight needed; U=16 gives
// 48 loads x 256 B x 256 waves ~ 3.1 MB. All indices compile-time (no scratch).
#define U_SC 16
__global__ __launch_bounds__(64) void scan_kernel(
    const float* __restrict__ C, const float* __restrict__ h0,
    const float* __restrict__ A_log, const float* __restrict__ r_delta,
    const float* __restrict__ bv, const float* __restrict__ bdl,
    const float* __restrict__ bgt, float* __restrict__ out) {
  int g = blockIdx.x * 64 + threadIdx.x;   // 256 blocks x 64 threads = B*D
  int d = g & 1023;
  float h  = h0[g];
  float rh = -__expf(A_log[d]);
  float rd = r_delta[d];
  float bb = bv[d], bd = bdl[d], bg = bgt[d];
  float* hout = out + (size_t)T_DIM * 16384;
  hout[g] = h;                              // h[0] = h0
  const float* Cb = C + (size_t)(g >> 10) * N3 + d;

  float pxv[U_SC], pxd[U_SC], pgp[U_SC];
#pragma unroll
  for (int u = 0; u < U_SC; ++u) {
    const float* cp = Cb + (size_t)u * 16 * N3;
    pxv[u] = cp[0]; pxd[u] = cp[1024]; pgp[u] = cp[2048];
  }

#pragma unroll 1
  for (int tg = 0; tg < T_DIM / U_SC; ++tg) {
    float cxv[U_SC], cxd[U_SC], cgp[U_SC];
#pragma unroll
    for (int u = 0; u < U_SC; ++u) { cxv[u] = pxv[u]; cxd[u] = pxd[u]; cgp[u] = pgp[u]; }
    if (tg + 1 < T_DIM / U_SC) {
      const float* nb = Cb + (size_t)(tg + 1) * U_SC * 16 * N3;
#pragma unroll
      for (int u = 0; u < U_SC; ++u) {
        const float* cp = nb + (size_t)u * 16 * N3;
        pxv[u] = cp[0]; pxd[u] = cp[1024]; pgp[u] = cp[2048];
      }
    }
#pragma unroll
    for (int u = 0; u < U_SC; ++u) {
      int t = tg * U_SC + u;
      float xv = cxv[u] + bb;
      float xd = cxd[u] + bd;
      float gp = cgp[u] + bg;
      float v     = fmaf(rh, h, xv);
      float delta = 1.0f / (1.0f + __expf(-(xd + rd * h)));
      float e2    = __expf(2.0f * v);
      float th    = 1.0f - 2.0f / (e2 + 1.0f);       // tanh(v), saturates correctly
      float hn    = fmaf(delta, th - h, h);          // (1-δ)h + δ·tanh(v)
      float gate  = gp / (1.0f + __expf(-gp));       // silu
      // write-once streams, never re-read: keep them out of L2's way
      __builtin_nontemporal_store(hn * gate, &out [(size_t)t       * 16384 + g]);
      __builtin_nontemporal_store(hn,        &hout[(size_t)(t + 1) * 16384 + g]);
      h = hn;
    }
  }
}

extern "C" void kernel_launch(void* const* d_in, const int* in_sizes, int n_in,
                              void* d_out, int out_size, void* d_ws, size_t ws_size,
                              hipStream_t stream) {
  const float* x       = (const float*)d_in[0];
  const float* h0      = (const float*)d_in[1];
  const float* A_log   = (const float*)d_in[2];
  const float* r_delta = (const float*)d_in[3];
  const float* W_x     = (const float*)d_in[4];
  const float* W_delta = (const float*)d_in[5];
  const float* W_gate  = (const float*)d_in[6];
  const float* b       = (const float*)d_in[7];
  const float* b_delta = (const float*)d_in[8];
  const float* b_gate  = (const float*)d_in[9];
  float* out = (float*)d_out;

  // workspace: Xs 134MB | Ws 12.6MB | C 402MB  (total ~524MB)
  u16*   Xs = (u16*)d_ws;
  u16*   Ws = (u16*)((char*)d_ws + (size_t)M_DIM * K2 * 2);
  float* C  = (float*)((char*)d_ws + (size_t)M_DIM * K2 * 2 + (size_t)N3 * K2 * 2);

  hipLaunchKernelGGL(cvt_x_kernel, dim3(32768), dim3(256), 0, stream, x, Xs);
  hipLaunchKernelGGL(cvt_w_kernel, dim3(3072),  dim3(256), 0, stream, W_x, W_delta, W_gate, Ws);
  hipLaunchKernelGGL(gemm_kernel,  dim3(6144),  dim3(256), 0, stream, Xs, Ws, C);
  hipLaunchKernelGGL(scan_kernel,  dim3(256),   dim3(64),  0, stream,
                     C, h0, A_log, r_delta, b, b_delta, b_gate, out);
}

// Round 10
// 1265.457 us; speedup vs baseline: 1.1111x; 1.1111x over previous
//
#include <hip/hip_runtime.h>

#define T_DIM 2048
#define B_DIM 16
#define D_DIM 1024
#define M_DIM (T_DIM * B_DIM)   // 32768 rows of x
#define K2    2048              // split K: [hi | lo]
#define N3    3072              // W_x | W_delta | W_gate output columns

typedef unsigned short u16;
typedef __bf16 bf16x8 __attribute__((ext_vector_type(8)));
typedef float  f32x4  __attribute__((ext_vector_type(4)));

typedef __attribute__((address_space(3))) uint32_t       lds_u32_t;
typedef const __attribute__((address_space(1))) uint32_t glb_u32_t;

__device__ inline void gload16(const void* g, void* l) {
  __builtin_amdgcn_global_load_lds((glb_u32_t*)g, (lds_u32_t*)l, 16, 0, 0);
}
__device__ inline void gload4(const void* g, void* l) {
  __builtin_amdgcn_global_load_lds((glb_u32_t*)g, (lds_u32_t*)l, 4, 0, 0);
}

// bf16 round-to-nearest-even, bit-level (inputs finite)
__device__ inline u16 f2bf_u(float f) {
  uint32_t u = __float_as_uint(f);
  uint32_t r = (u + 0x7FFFu + ((u >> 16) & 1u)) >> 16;
  return (u16)r;
}
__device__ inline float bfu2f(u16 u) {
  return __uint_as_float(((uint32_t)u) << 16);
}

// fast approx reciprocal: single v_rcp_f32 (~8 cyc) instead of the precise
// div chain (~40+ cyc serial). rel err ~1e-7 << pipeline's 3.9e-3 absmax.
// rcp(inf)=0 so exp-overflow saturates sigmoids correctly.
__device__ inline float fast_rcp(float x) { return __builtin_amdgcn_rcpf(x); }

// ---------------- convert x -> Xs [M, 2048] bf16 (hi | lo) ----------------
__global__ void cvt_x_kernel(const float* __restrict__ x, u16* __restrict__ Xs) {
  int i = blockIdx.x * 256 + threadIdx.x;          // 8,388,608 float4s
  int m  = i >> 8;                                 // 256 float4 per row
  int c4 = (i & 255) << 2;
  float4 v = reinterpret_cast<const float4*>(x)[i];
  float f[4] = {v.x, v.y, v.z, v.w};
  u16 hi[4], lo[4];
#pragma unroll
  for (int j = 0; j < 4; ++j) {
    hi[j] = f2bf_u(f[j]);
    lo[j] = f2bf_u(f[j] - bfu2f(hi[j]));
  }
  u16* base = Xs + (size_t)m * K2 + c4;
  *reinterpret_cast<ushort4*>(base)        = make_ushort4(hi[0], hi[1], hi[2], hi[3]);
  *reinterpret_cast<ushort4*>(base + 1024) = make_ushort4(lo[0], lo[1], lo[2], lo[3]);
}

// ------------- convert W_x|W_delta|W_gate -> Ws [3072, 2048] --------------
__global__ void cvt_w_kernel(const float* __restrict__ Wx, const float* __restrict__ Wd,
                             const float* __restrict__ Wg, u16* __restrict__ Ws) {
  int i = blockIdx.x * 256 + threadIdx.x;          // 786,432 float4s
  int n  = i >> 8;                                 // 0..3071
  int c4 = (i & 255) << 2;
  const float* W = (n < 1024) ? Wx : (n < 2048 ? Wd : Wg);
  int row = n & 1023;
  float4 v = reinterpret_cast<const float4*>(W)[(size_t)row * 256 + (i & 255)];
  float f[4] = {v.x, v.y, v.z, v.w};
  u16 hi[4], lo[4];
#pragma unroll
  for (int j = 0; j < 4; ++j) {
    hi[j] = f2bf_u(f[j]);
    lo[j] = f2bf_u(f[j] - bfu2f(hi[j]));
  }
  u16* base = Ws + (size_t)n * K2 + c4;
  *reinterpret_cast<ushort4*>(base)        = make_ushort4(hi[0], hi[1], hi[2], hi[3]);
  *reinterpret_cast<ushort4*>(base + 1024) = make_ushort4(lo[0], lo[1], lo[2], lo[3]);
}

// ---------------- GEMM: C[32768, 3072] = Xs · Wsᵀ (split 3-pass) ----------
// MEASURED R6: 700 us, 884 TF, MfmaUtil 40.2%, bank-conflict 0 — at the m97
// structure's known ceiling. Byte-identical since R6.
__global__ __launch_bounds__(256) void gemm_kernel(const u16* __restrict__ Xs,
                                                   const u16* __restrict__ Ws,
                                                   float* __restrict__ C) {
  __shared__ __align__(16) u16 As[128 * 64];
  __shared__ __align__(16) u16 Bs[128 * 64];

  int bid = blockIdx.x;
  int swz = (bid & 7) * 768 + (bid >> 3);   // 6144 % 8 == 0 -> bijective
  int nt = swz >> 8;                        // 0..23
  int mt = swz & 255;                       // 0..255
  int tid  = threadIdx.x;
  int lane = tid & 63;
  int wid  = tid >> 6;
  int wr = wid >> 1, wc = wid & 1;
  int r16 = lane & 15, grp = lane >> 4;

  f32x4 acc[4][4];
#pragma unroll
  for (int m = 0; m < 4; ++m)
#pragma unroll
    for (int n = 0; n < 4; ++n)
#pragma unroll
      for (int e = 0; e < 4; ++e) acc[m][n][e] = 0.0f;

  const u16* Abase = Xs + (size_t)mt * 128 * K2;
  const u16* Bbase = Ws + (size_t)nt * 128 * K2;

#pragma unroll 1
  for (int p = 0; p < 3; ++p) {
    const u16* Ap = Abase + (p == 2 ? 1024 : 0);  // passes: hi·hi, hi·lo, lo·hi
    const u16* Bp = Bbase + (p == 1 ? 1024 : 0);
#pragma unroll 1
    for (int kt = 0; kt < 16; ++kt) {
      __syncthreads();  // all waves done reading previous tile
#pragma unroll
      for (int i = 0; i < 4; ++i) {
        int slot = i * 256 + tid;
        int row  = slot >> 3;
        int c    = (slot & 7) ^ (row & 7);
        gload16(Ap + (size_t)row * K2 + kt * 64 + c * 8,
                &As[(size_t)(i * 256 + wid * 64) * 8]);
      }
#pragma unroll
      for (int i = 0; i < 4; ++i) {
        int slot = i * 256 + tid;
        int row  = slot >> 3;
        int c    = (slot & 7) ^ (row & 7);
        gload16(Bp + (size_t)row * K2 + kt * 64 + c * 8,
                &Bs[(size_t)(i * 256 + wid * 64) * 8]);
      }
      __syncthreads();  // drains vmcnt(0): staged data visible
#pragma unroll
      for (int ks = 0; ks < 2; ++ks) {
        bf16x8 af[4], bfr[4];
#pragma unroll
        for (int m = 0; m < 4; ++m) {
          int row = wr * 64 + m * 16 + r16;
          int ch  = (ks * 4 + grp) ^ (row & 7);
          af[m] = *reinterpret_cast<const bf16x8*>(&As[row * 64 + ch * 8]);
        }
#pragma unroll
        for (int n = 0; n < 4; ++n) {
          int row = wc * 64 + n * 16 + r16;
          int ch  = (ks * 4 + grp) ^ (row & 7);
          bfr[n] = *reinterpret_cast<const bf16x8*>(&Bs[row * 64 + ch * 8]);
        }
#pragma unroll
        for (int m = 0; m < 4; ++m)
#pragma unroll
          for (int n = 0; n < 4; ++n)
            acc[m][n] = __builtin_amdgcn_mfma_f32_16x16x32_bf16(af[m], bfr[n], acc[m][n], 0, 0, 0);
      }
    }
  }

  // epilogue: C/D layout col = lane&15, row = (lane>>4)*4 + reg  [HW-verified]
  size_t baseRow = (size_t)mt * 128 + wr * 64 + grp * 4;
  int    baseCol = nt * 128 + wc * 64 + r16;
#pragma unroll
  for (int m = 0; m < 4; ++m)
#pragma unroll
    for (int reg = 0; reg < 4; ++reg) {
      float* crow = C + (baseRow + m * 16 + reg) * (size_t)N3 + baseCol;
#pragma unroll
      for (int n = 0; n < 4; ++n) crow[n * 16] = acc[m][n][reg];
    }
}

// ---------------- scan: 16384 independent chains over T=2048 --------------
// R7 post-mortem: register-prefetch gave NO load/compute overlap (serial-chain
// time converts 1:1 to wall time; scan ~560us). Rewrite: global_load_lds DMA
// staging (no dest VGPRs -> compiler cannot serialize the loads), LDS double
// buffer sb[2][16 steps][3 streams][64 lanes] = 24KB, one vmcnt(0) per group.
// Single wave/block: no barriers needed. Normal stores (nt removed: nt writes
// bypassing L2 race against the harness's dirty 0xAA poison lines -> the R7
// post-timing divergence).
#define TG 16
__global__ __launch_bounds__(64) void scan_kernel(
    const float* __restrict__ C, const float* __restrict__ h0,
    const float* __restrict__ A_log, const float* __restrict__ r_delta,
    const float* __restrict__ bv, const float* __restrict__ bdl,
    const float* __restrict__ bgt, float* __restrict__ out) {
  __shared__ __align__(16) float sb[2][TG][3][64];
  int tid = threadIdx.x;
  int bid = blockIdx.x;
  int g = bid * 64 + tid;                  // 256 blocks x 64 = B*D chains
  int d = g & 1023;
  int b = g >> 10;                         // batch index (uniform per block)
  float h  = h0[g];
  float rh = -__expf(A_log[d]);
  float rd = r_delta[d];
  float bb = bv[d], bd = bdl[d], bg = bgt[d];
  float* hout = out + (size_t)T_DIM * 16384;
  hout[g] = h;                             // h[0] = h0
  // per-lane source: row (t*16+b) of C, columns dbase..dbase+63 (+c*1024)
  const float* Crow = C + (size_t)b * N3 + (d - tid) + tid;

  // prologue: stage group 0 into buffer 0
#pragma unroll
  for (int u = 0; u < TG; ++u)
#pragma unroll
    for (int c = 0; c < 3; ++c)
      gload4(Crow + ((size_t)u * 16) * N3 + c * 1024, &sb[0][u][c][0]);
  asm volatile("s_waitcnt vmcnt(0)" ::: "memory");
  __builtin_amdgcn_sched_barrier(0);

#pragma unroll 1
  for (int tg = 0; tg < T_DIM / TG; ++tg) {
    int buf = tg & 1;
    if (tg + 1 < T_DIM / TG) {             // async stage of next group
      const float* nb = Crow + ((size_t)(tg + 1) * TG * 16) * N3;
#pragma unroll
      for (int u = 0; u < TG; ++u)
#pragma unroll
        for (int c = 0; c < 3; ++c)
          gload4(nb + ((size_t)u * 16) * N3 + c * 1024, &sb[buf ^ 1][u][c][0]);
    }
#pragma unroll
    for (int u = 0; u < TG; ++u) {
      int t = tg * TG + u;
      float xv = sb[buf][u][0][tid] + bb;
      float xd = sb[buf][u][1][tid] + bd;
      float gp = sb[buf][u][2][tid] + bg;
      float v     = fmaf(rh, h, xv);
      float sarg  = fmaf(rd, h, xd);
      float delta = fast_rcp(1.0f + __expf(-sarg));          // sigmoid
      float e2    = __expf(2.0f * v);
      float th    = fmaf(-2.0f, fast_rcp(e2 + 1.0f), 1.0f);  // tanh(v)
      float hn    = fmaf(delta, th - h, h);                  // (1-δ)h + δ·tanh(v)
      float gate  = gp * fast_rcp(1.0f + __expf(-gp));       // silu
      out [(size_t)t       * 16384 + g] = hn * gate;
      hout[(size_t)(t + 1) * 16384 + g] = hn;
      h = hn;
    }
    // next group's DMA must have landed before we read it next iteration
    asm volatile("s_waitcnt vmcnt(0)" ::: "memory");
    __builtin_amdgcn_sched_barrier(0);
  }
}

extern "C" void kernel_launch(void* const* d_in, const int* in_sizes, int n_in,
                              void* d_out, int out_size, void* d_ws, size_t ws_size,
                              hipStream_t stream) {
  const float* x       = (const float*)d_in[0];
  const float* h0      = (const float*)d_in[1];
  const float* A_log   = (const float*)d_in[2];
  const float* r_delta = (const float*)d_in[3];
  const float* W_x     = (const float*)d_in[4];
  const float* W_delta = (const float*)d_in[5];
  const float* W_gate  = (const float*)d_in[6];
  const float* b       = (const float*)d_in[7];
  const float* b_delta = (const float*)d_in[8];
  const float* b_gate  = (const float*)d_in[9];
  float* out = (float*)d_out;

  // workspace: Xs 134MB | Ws 12.6MB | C 402MB  (total ~524MB)
  u16*   Xs = (u16*)d_ws;
  u16*   Ws = (u16*)((char*)d_ws + (size_t)M_DIM * K2 * 2);
  float* C  = (float*)((char*)d_ws + (size_t)M_DIM * K2 * 2 + (size_t)N3 * K2 * 2);

  hipLaunchKernelGGL(cvt_x_kernel, dim3(32768), dim3(256), 0, stream, x, Xs);
  hipLaunchKernelGGL(cvt_w_kernel, dim3(3072),  dim3(256), 0, stream, W_x, W_delta, W_gate, Ws);
  hipLaunchKernelGGL(gemm_kernel,  dim3(6144),  dim3(256), 0, stream, Xs, Ws, C);
  hipLaunchKernelGGL(scan_kernel,  dim3(256),   dim3(64),  0, stream,
                     C, h0, A_log, r_delta, b, b_delta, b_gate, out);
}